// Round 6
// baseline (472.751 us; speedup 1.0000x reference)
//
#include <hip/hip_runtime.h>
#include <math.h>

#define Bc 16
#define Nc 4096

typedef __attribute__((ext_vector_type(8))) short short8;
typedef __attribute__((ext_vector_type(4))) float floatx4;

__device__ __forceinline__ unsigned short f2bf(float f) {
    union { float f; unsigned int u; } v; v.f = f;
    unsigned int u = v.u;
    return (unsigned short)((u + 0x7fffu + ((u >> 16) & 1u)) >> 16);
}
__device__ __forceinline__ float bf2f(unsigned short u) {
    union { unsigned int u; float f; } v; v.u = ((unsigned int)u) << 16;
    return v.f;
}

// async global->LDS 16B/lane; LDS dest must be wave-uniform base + lane*16
__device__ __forceinline__ void gll16(const unsigned short* g, unsigned short* l) {
    __builtin_amdgcn_global_load_lds(
        (const __attribute__((address_space(1))) void*)g,
        (__attribute__((address_space(3))) void*)l,
        16, 0, 0);
}

// ---------------------------------------------------------------------------
// Swapped-operand bf16 GEMM, 512 threads, tile 128(M)x256(N), BK=64.
// mfma(wf, af, acc): D col = quad*4+rg (vector stores), D row = l16.
// XOR-granule LDS swizzle (bank-conflict-free, gll16-compatible).
// EPI 1: + column sum-of-squares -> norm2              (G2)
// EPI 2: A staged with scale -Pi*attn(S,T) (VALU)      (G3)
// EPI 3: + bf16 residual, fp32 out                     (G5)
// EPI 4: + per-row sum/sumsq -> rowstats               (G4)
// EPI 5: rope epilogue: acc 4-tuple = (s0,s1,v0,v1) of pair j=cb/4 -> wi bf16
// ---------------------------------------------------------------------------
template <int EPI, typename TOUT>
__global__ __launch_bounds__(512) void gemm_bf(
    const unsigned short* __restrict__ A0, int lda0,
    const unsigned short* __restrict__ A1, int lda1, int K0,
    const unsigned short* __restrict__ W,
    const float* __restrict__ bias,
    const unsigned short* __restrict__ resid_bf,   // EPI3
    const float* __restrict__ Pi,                  // EPI2
    const float* __restrict__ Sb,                  // EPI2
    const float* __restrict__ Tb,                  // EPI2
    const float* __restrict__ enc,                 // EPI5
    float* __restrict__ norm2,                     // EPI1
    float* __restrict__ rowstats,                  // EPI4
    TOUT* __restrict__ C, int N, int K)
{
    __shared__ alignas(16) unsigned short As[128 * 64];
    __shared__ alignas(16) unsigned short Bs[256 * 64];

    const int t = threadIdx.x;
    const int bn = blockIdx.x, bm = blockIdx.y;
    const int lane = t & 63, wave = t >> 6;          // 8 waves
    const int wm = wave >> 2, wn = wave & 3;         // 2 x 4
    const int quad = lane >> 4, l16 = lane & 15;
    const int rt = t >> 3, st = t & 7;               // rt 0..63

    floatx4 acc[4][4];
    #pragma unroll
    for (int i = 0; i < 4; ++i)
        #pragma unroll
        for (int j = 0; j < 4; ++j)
            acc[i][j] = (floatx4){0.f, 0.f, 0.f, 0.f};

    for (int k0 = 0; k0 < K; k0 += 64) {
        // A tile: 128 rows x 64
        #pragma unroll
        for (int hh = 0; hh < 2; ++hh) {
            const int row = hh * 64 + rt;
            const int col = k0 + (st ^ (row & 7)) * 8;
            unsigned short* ldsa = As + row * 64 + st * 8;
            const size_t grow = (size_t)bm * 128 + row;
            if constexpr (EPI == 2) {
                const int b = (int)(grow >> 12);
                const int hd = col >> 6;
                const float s = Sb[b * 4 + hd] + 1e-8f;
                const float at = s / (s + Tb[b * 4 + hd]);
                const float sc = -Pi[grow * 4 + hd] * at;
                const short8 a = *(const short8*)(A0 + grow * (size_t)lda0 + col);
                short8 o;
                #pragma unroll
                for (int j = 0; j < 8; ++j) o[j] = (short)f2bf(bf2f((unsigned short)a[j]) * sc);
                *(short8*)ldsa = o;
            } else {
                const unsigned short* src = (col < K0)
                    ? (A0 + grow * (size_t)lda0 + col)
                    : (A1 + grow * (size_t)lda1 + (col - K0));
                gll16(src, ldsa);
            }
        }
        // W tile: 256 rows x 64
        #pragma unroll
        for (int hh = 0; hh < 4; ++hh) {
            const int row = hh * 64 + rt;
            const int col = k0 + (st ^ (row & 7)) * 8;
            gll16(W + ((size_t)bn * 256 + row) * (size_t)K + col, Bs + row * 64 + st * 8);
        }
        __syncthreads();
        #pragma unroll
        for (int kk = 0; kk < 2; ++kk) {
            short8 af[4], wf[4];
            #pragma unroll
            for (int i = 0; i < 4; ++i) {
                const int ra = wm * 64 + i * 16 + l16;
                af[i] = *(const short8*)(As + ra * 64 + ((quad + kk * 4) ^ (ra & 7)) * 8);
                const int rw = wn * 64 + i * 16 + l16;
                wf[i] = *(const short8*)(Bs + rw * 64 + ((quad + kk * 4) ^ (rw & 7)) * 8);
            }
            #pragma unroll
            for (int mi = 0; mi < 4; ++mi)
                #pragma unroll
                for (int ni = 0; ni < 4; ++ni)
                    acc[mi][ni] = __builtin_amdgcn_mfma_f32_16x16x32_bf16(
                        wf[ni], af[mi], acc[mi][ni], 0, 0, 0);
        }
        __syncthreads();
    }

    // epilogue: row = bm*128+wm*64+mi*16+l16; col = bn*256+wn*64+ni*16+quad*4+rg
    float rs[4], rq[4];
    if constexpr (EPI == 4) {
        #pragma unroll
        for (int m = 0; m < 4; ++m) { rs[m] = 0.f; rq[m] = 0.f; }
    }

    #pragma unroll
    for (int mi = 0; mi < 4; ++mi) {
        const size_t row = (size_t)bm * 128 + wm * 64 + mi * 16 + l16;
        #pragma unroll
        for (int ni = 0; ni < 4; ++ni) {
            const int cb = bn * 256 + wn * 64 + ni * 16 + quad * 4;
            const float4 b4 = *(const float4*)(bias + cb);
            if constexpr (EPI == 5) {
                // acc 4-tuple = (s0, s1, v0, v1) for pair j = cb>>2
                const int j = cb >> 2;
                const int h = j >> 5, d = (j & 31) * 2;
                const float s0 = acc[mi][ni][0] + b4.x;
                const float s1 = acc[mi][ni][1] + b4.y;
                const float v0 = acc[mi][ni][2] + b4.z;
                const float v1 = acc[mi][ni][3] + b4.w;
                const float2 e0 = *(const float2*)(enc + row * 64 + d);
                const float2 e1 = *(const float2*)(enc + 4194304 + row * 64 + d);
                const float r0 = s0 * e0.x - s1 * e1.x;
                const float r1 = s1 * e0.y + s0 * e1.y;
                ushort2 o;
                o.x = f2bf((r0 + v0) * (1.f / 3.f));
                o.y = f2bf((r1 + v1) * (1.f / 3.f));
                *(ushort2*)((unsigned short*)C + row * 256 + h * 64 + d) = o;
                continue;
            }
            float v[4] = {acc[mi][ni][0] + b4.x, acc[mi][ni][1] + b4.y,
                          acc[mi][ni][2] + b4.z, acc[mi][ni][3] + b4.w};
            if constexpr (EPI == 3) {
                const ushort4 xr = *(const ushort4*)(resid_bf + row * (size_t)N + cb);
                v[0] += bf2f(xr.x); v[1] += bf2f(xr.y);
                v[2] += bf2f(xr.z); v[3] += bf2f(xr.w);
            }
            if constexpr (EPI == 4) {
                #pragma unroll
                for (int rg = 0; rg < 4; ++rg) { rs[mi] += v[rg]; rq[mi] += v[rg] * v[rg]; }
            }
            if constexpr (EPI == 1) {
                #pragma unroll
                for (int rg = 0; rg < 4; ++rg) {
                    float s = v[rg] * v[rg];
                    s += __shfl_xor(s, 1, 64);
                    s += __shfl_xor(s, 2, 64);
                    s += __shfl_xor(s, 4, 64);
                    s += __shfl_xor(s, 8, 64);
                    if (l16 == 0) atomicAdd(&norm2[(bm >> 5) * 256 + cb + rg], s);
                }
            }
            if constexpr (__is_same(TOUT, float)) {
                float4 o; o.x = v[0]; o.y = v[1]; o.z = v[2]; o.w = v[3];
                *(float4*)(C + row * (size_t)N + cb) = o;
            } else {
                ushort4 o;
                o.x = f2bf(v[0]); o.y = f2bf(v[1]); o.z = f2bf(v[2]); o.w = f2bf(v[3]);
                *(ushort4*)(C + row * (size_t)N + cb) = o;
            }
        }
    }
    if constexpr (EPI == 4) {
        #pragma unroll
        for (int mi = 0; mi < 4; ++mi) {
            float s = rs[mi], q = rq[mi];
            s += __shfl_xor(s, 16, 64); s += __shfl_xor(s, 32, 64);
            q += __shfl_xor(q, 16, 64); q += __shfl_xor(q, 32, 64);
            if (quad == 0) {
                const size_t row = (size_t)bm * 128 + wm * 64 + mi * 16 + l16;
                atomicAdd(&rowstats[row * 2], s);
                atomicAdd(&rowstats[row * 2 + 1], q);
            }
        }
    }
}

// ---------------------------------------------------------------------------
// LN(512)+exact gelu streaming pass using precomputed rowstats
// ---------------------------------------------------------------------------
__global__ __launch_bounds__(256) void lngelu_kernel(unsigned short* __restrict__ h1,
                                                     const float* __restrict__ rowstats,
                                                     const float* __restrict__ g,
                                                     const float* __restrict__ bb) {
    const size_t gid = (size_t)blockIdx.x * 256 + threadIdx.x;
    const size_t row = gid >> 6;
    const int col = (int)(gid & 63) * 8;
    const float2 stv = *(const float2*)(rowstats + row * 2);
    const float mean = stv.x * (1.f / 512.f);
    const float var = stv.y * (1.f / 512.f) - mean * mean;
    const float rstd = rsqrtf(var + 1e-5f);
    unsigned short* p = h1 + row * 512 + col;
    const short8 hv = *(const short8*)p;
    const float4 g0 = *(const float4*)(g + col);
    const float4 g1 = *(const float4*)(g + col + 4);
    const float4 b0 = *(const float4*)(bb + col);
    const float4 b1 = *(const float4*)(bb + col + 4);
    const float vg[8] = {g0.x, g0.y, g0.z, g0.w, g1.x, g1.y, g1.z, g1.w};
    const float vb[8] = {b0.x, b0.y, b0.z, b0.w, b1.x, b1.y, b1.z, b1.w};
    short8 ov;
    #pragma unroll
    for (int k = 0; k < 8; ++k) {
        const float ln = (bf2f((unsigned short)hv[k]) - mean) * rstd * vg[k] + vb[k];
        ov[k] = (short)f2bf(0.5f * ln * (1.f + erff(ln * 0.70710678118654752f)));
    }
    *(short8*)p = ov;
}

// ---------------------------------------------------------------------------
// single prep kernel: converts + fused weights + zeroing
// Wsvq interleaved: row 4j+m (j in [0,128)): m=0,1 -> s_{2j},s_{2j+1};
// m=2,3 -> v_{2j},v_{2j+1}. s_c = Wq_c + Wk_c (rope-sum), v_c = Wv_c.
// ---------------------------------------------------------------------------
__device__ __forceinline__ void conv8(const float* src, unsigned short* dst, int i) {
    const float4 f0 = *(const float4*)(src + (size_t)i * 8);
    const float4 f1 = *(const float4*)(src + (size_t)i * 8 + 4);
    short8 sv;
    sv[0] = (short)f2bf(f0.x); sv[1] = (short)f2bf(f0.y);
    sv[2] = (short)f2bf(f0.z); sv[3] = (short)f2bf(f0.w);
    sv[4] = (short)f2bf(f1.x); sv[5] = (short)f2bf(f1.y);
    sv[6] = (short)f2bf(f1.z); sv[7] = (short)f2bf(f1.w);
    *(short8*)(dst + (size_t)i * 8) = sv;
}

__global__ __launch_bounds__(256) void prep_all(
    const float* __restrict__ x, const float* __restrict__ Wqkv,
    const float* __restrict__ bqkv, const float* __restrict__ tssa_w,
    const float* __restrict__ op_w, const float* __restrict__ to_w,
    const float* __restrict__ to_b, const float* __restrict__ op_b,
    const float* __restrict__ f1w, const float* __restrict__ f2w,
    unsigned short* __restrict__ x_bf, unsigned short* __restrict__ Wsvq,
    float* __restrict__ bsvq, unsigned short* __restrict__ tssa_bf,
    unsigned short* __restrict__ Wf, float* __restrict__ bfb,
    unsigned short* __restrict__ ffn1_bf, unsigned short* __restrict__ ffn2_bf,
    float* __restrict__ zbase, float* __restrict__ rowstats)
{
    const int blk = blockIdx.x, tt = threadIdx.x;
    if (blk < 8192) {
        conv8(x, x_bf, blk * 256 + tt);
    } else if (blk < 8704) {
        const int r = blk - 8192, c = tt;       // r 0..511
        const int j = r >> 2, m = r & 3;
        const int cc = 2 * j + (m & 1);
        const int h = cc >> 6, dd = cc & 63;
        const int base = h * 192 + dd * 3;
        if (m < 2) {
            Wsvq[r * 256 + c] = f2bf(Wqkv[(base + 0) * 256 + c] + Wqkv[(base + 1) * 256 + c]);
            if (c == 0) bsvq[r] = bqkv[base] + bqkv[base + 1];
        } else {
            Wsvq[r * 256 + c] = f2bf(Wqkv[(base + 2) * 256 + c]);
            if (c == 0) bsvq[r] = bqkv[base + 2];
        }
    } else if (blk < 8960) {
        const int i = blk - 8704;
        float s = 0.f;
        for (int k = 0; k < 256; ++k) s += op_w[i * 256 + k] * to_w[k * 256 + tt];
        Wf[i * 256 + tt] = f2bf(s);
    } else if (blk == 8960) {
        float s = op_b[tt];
        for (int k = 0; k < 256; ++k) s += op_w[tt * 256 + k] * to_b[k];
        bfb[tt] = s;
    } else if (blk < 8993) {
        conv8(tssa_w, tssa_bf, (blk - 8961) * 256 + tt);
    } else if (blk < 9121) {
        conv8(f1w, ffn1_bf, (blk - 8993) * 256 + tt);
    } else if (blk < 9185) {
        conv8(f2w, ffn2_bf, (blk - 9121) * 256 + tt);
    } else {
        const int i = (blk - 9185) * 256 + tt;
        if (i < 4288) zbase[i] = 0.f;
        else if (i < 135360) rowstats[i - 4288] = 0.f;
    }
}

// ---------------------------------------------------------------------------
// per-row softmax over heads + S/T accumulation
// ---------------------------------------------------------------------------
__global__ __launch_bounds__(256) void pi_kernel(const unsigned short* __restrict__ w,
                                                 const float* __restrict__ norm2,
                                                 const float* __restrict__ temp,
                                                 float* __restrict__ Pi,
                                                 float* __restrict__ S,
                                                 float* __restrict__ T) {
    const int t = threadIdx.x;
    const int i = t & 15;
    const int lr = t >> 4;
    const size_t r = (size_t)blockIdx.x * 16 + lr;
    const int b = (int)(r >> 12);
    const unsigned short* wrow = w + r * 256;
    const float* n2row = norm2 + b * 256;
    float raw[4], nrm[4];
    #pragma unroll
    for (int h = 0; h < 4; ++h) {
        const ushort4 wv = *(const ushort4*)(wrow + h * 64 + i * 4);
        const float w0 = bf2f(wv.x), w1 = bf2f(wv.y), w2 = bf2f(wv.z), w3 = bf2f(wv.w);
        const float4 n2 = *(const float4*)(n2row + h * 64 + i * 4);
        const float s0 = w0 * w0, s1 = w1 * w1, s2 = w2 * w2, s3 = w3 * w3;
        raw[h] = s0 + s1 + s2 + s3;
        nrm[h] = s0 / fmaxf(n2.x, 1e-24f) + s1 / fmaxf(n2.y, 1e-24f)
               + s2 / fmaxf(n2.z, 1e-24f) + s3 / fmaxf(n2.w, 1e-24f);
    }
    #pragma unroll
    for (int off = 1; off < 16; off <<= 1) {
        #pragma unroll
        for (int h = 0; h < 4; ++h) {
            raw[h] += __shfl_xor(raw[h], off, 64);
            nrm[h] += __shfl_xor(nrm[h], off, 64);
        }
    }
    float sw[4], m = -1e30f;
    #pragma unroll
    for (int h = 0; h < 4; ++h) { sw[h] = nrm[h] * temp[h]; m = fmaxf(m, sw[h]); }
    float e[4], Z = 0.f;
    #pragma unroll
    for (int h = 0; h < 4; ++h) { e[h] = expf(sw[h] - m); Z += e[h]; }
    const float invZ = 1.f / Z;
    float pi[4];
    #pragma unroll
    for (int h = 0; h < 4; ++h) pi[h] = e[h] * invZ;
    if (i < 4) Pi[r * 4 + i] = pi[i];

    __shared__ float sS[16][4], sT[16][4];
    if (i == 0) {
        #pragma unroll
        for (int h = 0; h < 4; ++h) { sS[lr][h] = pi[h]; sT[lr][h] = pi[h] * raw[h]; }
    }
    __syncthreads();
    if (t < 4) {
        float as = 0.f, at = 0.f;
        for (int rr = 0; rr < 16; ++rr) { as += sS[rr][t]; at += sT[rr][t]; }
        atomicAdd(&S[b * 4 + t], as);
        atomicAdd(&T[b * 4 + t], at);
    }
}

// ---------------------------------------------------------------------------
extern "C" void kernel_launch(void* const* d_in, const int* in_sizes, int n_in,
                              void* d_out, int out_size, void* d_ws, size_t ws_size,
                              hipStream_t stream) {
    (void)in_sizes; (void)n_in; (void)out_size; (void)ws_size;
    const float* x          = (const float*)d_in[0];
    const float* enc        = (const float*)d_in[1];
    const float* Wqkv_w     = (const float*)d_in[2];
    const float* Wqkv_b     = (const float*)d_in[3];
    const float* tssa_qkv_w = (const float*)d_in[4];
    const float* tssa_qkv_b = (const float*)d_in[5];
    const float* temp       = (const float*)d_in[6];
    const float* tssa_out_w = (const float*)d_in[7];
    const float* tssa_out_b = (const float*)d_in[8];
    const float* out_proj_w = (const float*)d_in[9];
    const float* out_proj_b = (const float*)d_in[10];
    const float* ffn1_w     = (const float*)d_in[11];
    const float* ffn1_b     = (const float*)d_in[12];
    const float* ln_g       = (const float*)d_in[13];
    const float* ln_b       = (const float*)d_in[14];
    const float* ffn2_w     = (const float*)d_in[15];
    const float* ffn2_b     = (const float*)d_in[16];
    float* outp = (float*)d_out;

    const int M = Bc * Nc;  // 65536

    char* ws = (char*)d_ws;
    unsigned short* x_bf  = (unsigned short*)(ws);
    unsigned short* wi_bf = (unsigned short*)(ws + (size_t)(32 << 20));
    unsigned short* h1_bf = (unsigned short*)(ws + (size_t)(32 << 20));
    unsigned short* w_bf  = (unsigned short*)(ws + (size_t)(64 << 20));
    unsigned short* msg_bf= (unsigned short*)(ws + (size_t)(96 << 20));
    float* fb    = (float*)(ws + (size_t)(128 << 20));
    float* Pi    = fb;                 // 262144
    float* norm2 = Pi + 262144;        // 4096  <- zero base
    float* Sb    = norm2 + 4096;       // 64
    float* Tb    = Sb + 64;            // 64
    float* attnb = Tb + 64;            // 64 (unused, layout keep)
    float* bsvq  = attnb + 64;         // 512
    float* bfb   = bsvq + 512;         // 256
    float* rowstats = bfb + 256;       // 131072
    unsigned short* Wsvq_bf = (unsigned short*)(rowstats + 131072);
    unsigned short* tssa_bf = Wsvq_bf + 131072;
    unsigned short* Wf_bf   = tssa_bf + 65536;
    unsigned short* ffn1_bf = Wf_bf + 65536;
    unsigned short* ffn2_bf = ffn1_bf + 262144;

    // 1. prep
    prep_all<<<9714, 256, 0, stream>>>(
        x, Wqkv_w, Wqkv_b, tssa_qkv_w, out_proj_w, tssa_out_w, tssa_out_b,
        out_proj_b, ffn1_w, ffn2_w,
        x_bf, Wsvq_bf, bsvq, tssa_bf, Wf_bf, bfb, ffn1_bf, ffn2_bf,
        norm2, rowstats);

    // 2. G1: wi = rope-combine(x_bf @ Wsvq^T + b)  (EPI5, N'=512 interleaved)
    gemm_bf<5, unsigned short><<<dim3(2, M / 128), 512, 0, stream>>>(
        x_bf, 256, x_bf, 256, 256, Wsvq_bf, bsvq,
        nullptr, nullptr, nullptr, nullptr, enc, nullptr, nullptr,
        wi_bf, 256, 256);

    // 3. G2: w = wi @ tssa^T + b -> bf16, fused colsq -> norm2
    gemm_bf<1, unsigned short><<<dim3(1, M / 128), 512, 0, stream>>>(
        wi_bf, 256, wi_bf, 256, 256, tssa_bf, tssa_qkv_b,
        nullptr, nullptr, nullptr, nullptr, nullptr, norm2, nullptr,
        w_bf, 256, 256);

    // 4. stats
    pi_kernel<<<4096, 256, 0, stream>>>(w_bf, norm2, temp, Pi, Sb, Tb);

    // 5. G3: message = (-w*Pi*attn(S,T)) @ Wf^T + bfb
    gemm_bf<2, unsigned short><<<dim3(1, M / 128), 512, 0, stream>>>(
        w_bf, 256, w_bf, 256, 256, Wf_bf, bfb,
        nullptr, Pi, Sb, Tb, nullptr, nullptr, nullptr,
        msg_bf, 256, 256);

    // 6. G4: h1 = [x_bf, msg] @ ffn1^T + b -> bf16, fused row sum/sumsq
    gemm_bf<4, unsigned short><<<dim3(2, M / 128), 512, 0, stream>>>(
        x_bf, 256, msg_bf, 256, 256, ffn1_bf, ffn1_b,
        nullptr, nullptr, nullptr, nullptr, nullptr, nullptr, rowstats,
        h1_bf, 512, 512);

    // 7. LN+gelu streaming (rowstats precomputed)
    lngelu_kernel<<<16384, 256, 0, stream>>>(h1_bf, rowstats, ln_g, ln_b);

    // 8. G5: out = x + gelu(LN(h1)) @ ffn2^T + b (fp32 out, bf16 residual)
    gemm_bf<3, float><<<dim3(1, M / 128), 512, 0, stream>>>(
        h1_bf, 512, h1_bf, 512, 512, ffn2_bf, ffn2_b,
        x_bf, nullptr, nullptr, nullptr, nullptr, nullptr, nullptr,
        outp, 256, 512);
}